// Round 13
// baseline (69.522 us; speedup 1.0000x reference)
//
#include <hip/hip_runtime.h>
#include <math.h>

#define HW 256
#define MINNORM 1.17549435e-38f   // 2^-126, f32 min normal

// One wave (64 lanes) per batch element; lane l owns count-support j = l.
// np ref semantics (verified R4..R12): XLA-CPU f32, FTZ/DAZ, pow underflow at
// j=42 -> support lives in [0,41].
// HARD-WON:
//  R10: death timing rides on per-step renormalized FTZ flush events — flushes
//       must happen at ref's exact points/scales (ulp noise OK, scale NOT).
//  R11: no cancellation forms for output p_z (S-p2 -> NaN near death).
//  R7/R12: issue-count and scheduling changes are NEUTRAL — the limiter is one
//       serial reduction round per step (~400 cyc incl. DPP/readlane hazards).
// R13: TWO steps per reduction round. csf/pg/mult are mask-determined, so a
//  pair's products a=cd*mult0, b=a*mult1 are formed before any reduction; one
//  dual reduction gives both norms (norm1 = Σb·invn0). HW mode = IEEE denorm
//  (so b doesn't over-flush — R10's failure mode); ref's FTZ replicated in
//  SOFTWARE at its exact points: af=flush(a), qf=flush(b·invn0), flush(cd').

template <int CTRL>
__device__ __forceinline__ float dpp_sra(float x) {
    // x + (x shifted toward higher lanes within each row of 16); OOB lanes add 0
    int s = __builtin_amdgcn_update_dpp(0, __builtin_bit_cast(int, x),
                                        CTRL, 0xf, 0xf, true);
    return x + __builtin_bit_cast(float, s);
}

__device__ __forceinline__ float rdlane(float x, int l) {
    return __builtin_bit_cast(float,
        __builtin_amdgcn_readlane(__builtin_bit_cast(int, x), l));
}

// Dual wave sum, stages interleaved (chains hide each other's hazard waits).
// Support lives in lanes 0..41; row 3 structurally zero -> dropped (bit-exact).
__device__ __forceinline__ void wave_total2(float x, float y,
                                            float& sx, float& sy) {
    x = dpp_sra<0x111>(x);  y = dpp_sra<0x111>(y);
    x = dpp_sra<0x112>(x);  y = dpp_sra<0x112>(y);
    x = dpp_sra<0x114>(x);  y = dpp_sra<0x114>(y);
    x = dpp_sra<0x118>(x);  y = dpp_sra<0x118>(y);
    const float a0 = rdlane(x, 15), b0 = rdlane(y, 15);
    const float a1 = rdlane(x, 31), b1 = rdlane(y, 31);
    const float a2 = rdlane(x, 47), b2 = rdlane(y, 47);
    sx = (a0 + a1) + a2;
    sy = (b0 + b1) + b2;
}

__global__ void __launch_bounds__(64, 1)
spair_count_kl(const float* __restrict__ z_pres,
               const float* __restrict__ z_prob,
               float* __restrict__ out) {
    // f32 denorm = IEEE preserve (FP_DENORM[1:0]=3): the composed pair needs
    // gradual underflow on the b path; ref's FTZ is replicated in software.
    float tok;
    asm volatile("s_setreg_imm32_b32 hwreg(HW_REG_MODE, 4, 2), 3\n\t"
                 "v_mov_b32 %0, 0" : "=v"(tok));

    const int lane = threadIdx.x;   // 0..63
    const int b = blockIdx.x;       // batch element

    // ---- cd0 init (explicit flushes; mode-independent): support cap j=41 ----
    const float e2f = (float)exp(2.0);                    // f32(exp(2))
    const float pf  = (float)(1.0 / ((double)e2f + 1.0)); // p in f32
    const double pd = (double)pf;
    const double l2p = log2(pd);
    float cd = 0.0f;
    if (lane <= 41) {
        const double powj = exp2((double)lane * l2p);      // accurate p^j
        float v = (float)((1.0 - pd) * powj);              // (1-p)*p^j, f32
        cd = (v < MINNORM) ? 0.0f : v;                     // j=41 survives
    }
    {
        float s = cd;
#pragma unroll
        for (int off = 32; off > 0; off >>= 1) s += __shfl_xor(s, off, 64);
        cd = cd / s;
    }
    cd += tok;                 // order the recurrence after the setreg
    const float jf = (float)lane;
    float csf = tok;           // 0.0f, ordered

    // per-lane CR 1/den registers (bit-identical to 1.0f/(float)(HW-i)):
    const float it0 = 1.0f / (float)(HW - lane);
    const float it1 = 1.0f / (float)(HW - 64 - lane);
    const float it2 = 1.0f / (float)(HW - 128 - lane);
    const float it3 = 1.0f / (float)(HW - 192 - lane);

    const float* presb = z_pres + (size_t)b * HW;
    const float* probb = z_prob + (size_t)b * HW;
    float* outb = out + (size_t)b * HW;

    bool dead = false;

#pragma unroll 1
    for (int k = 0; k < 4; ++k) {
        const float myprob = probb[k * 64 + lane];
        const float mypres = presb[k * 64 + lane];
        // sample = round(z_pres) in {0,1}; rintf = round-half-even = np.round
        const unsigned long long smask = __ballot(rintf(mypres) != 0.0f);
        float my_pz = 0.0f;
        const float itk = (k == 0) ? it0 : (k == 1) ? it1 : (k == 2) ? it2 : it3;

        if (!dead) {
#pragma unroll 1
            for (int blk = 0; blk < 4; ++blk) {
                float sent = 1.0f;   // last pair's raw norm1 (death sentinel)
#pragma unroll
                for (int pr = 0; pr < 8; ++pr) {
                    const int ii0 = blk * 16 + pr * 2, ii1 = ii0 + 1;
                    const int i0 = k * 64 + ii0;
                    const float fden0 = (float)(HW - i0);       // uniform
                    const float fden1 = (float)(HW - i0 - 1);   // uniform
                    const float inv0 = rdlane(itk, ii0);        // CR 1/den
                    const float inv1 = rdlane(itk, ii1);
                    const bool s0 = ((smask >> ii0) & 1ULL) != 0ULL;
                    const bool s1b = ((smask >> ii1) & 1ULL) != 0ULL;

                    // mask-determined pg/mult for BOTH steps (off-chain)
                    const float t0 = fminf(fmaxf(jf - csf, 0.0f), fden0);
                    const float pg0 = (t0 == fden0) ? 1.0f : t0 * inv0;
                    const float mult0 = s0 ? pg0 : (1.0f - pg0);
                    const float csfA = csf + (s0 ? 1.0f : 0.0f);
                    const float tA = fminf(fmaxf(jf - csfA, 0.0f), fden1);
                    const float pg1 = (tA == fden1) ? 1.0f : tA * inv1;
                    const float mult1 = s1b ? pg1 : (1.0f - pg1);

                    // ---- STATE CHAIN (flush points == ref's) ----
                    const float a_raw = cd * mult0;             // IEEE mul
                    const float af = (a_raw < MINNORM) ? 0.0f : a_raw; // ref flush t
                    const float b_raw = af * mult1;             // denorms preserved

                    // output-path products (noise-tolerant)
                    const float z0t = cd * pg0;
                    const float z1t = af * pg1;

                    float n0, n1raw, z0, z1;
                    wave_total2(af, b_raw, n0, n1raw);   // on-chain dual
                    wave_total2(z0t, z1t, z0, z1);       // off-chain dual

                    const float norm0 = fmaxf(n0, 1e-6f);
                    const float invn0 = __builtin_amdgcn_rcpf(norm0);
                    const float q = b_raw * invn0;       // ~= cd_{t+1}*mult1
                    const float qf = (q < MINNORM) ? 0.0f : q;  // ref flush t+1
                    const float norm1 = fmaxf(n1raw * invn0, 1e-6f);
                    const float invn1 = __builtin_amdgcn_rcpf(norm1);
                    const float cdn = qf * invn1;
                    cd = (cdn < MINNORM) ? 0.0f : cdn;   // division-edge flush
                    csf = csfA + (s1b ? 1.0f : 0.0f);

                    // ---- OUTPUT PATH ----
                    const float pz0 = z0;                // == norm presum on s1
                    const float pz1 = z1 * invn0;
                    my_pz = (ii0 == lane) ? pz0 : my_pz;
                    my_pz = (ii1 == lane) ? pz1 : my_pz;

                    sent = n1raw;
                }
                // Absorbing death: all pair-b terms exactly 0 (mult==0 exact)
                if (sent == 0.0f) { dead = true; break; }
            }
        }

        // KL for this lane's step (i = k*64 + lane); my_pz==0 on dead steps is
        // exactly the ref's p_z=0 closed form.
        const float prob = myprob;
        const float pz = my_pz;
        const float kl = prob * (logf(prob + 1e-9f) - logf(pz + 1e-9f))
                       + (1.0f - prob) * (logf((1.0f - prob) + 1e-9f)
                                        - logf((1.0f - pz) + 1e-9f));
        outb[k * 64 + lane] = kl;   // coalesced across the wave
    }
}

extern "C" void kernel_launch(void* const* d_in, const int* in_sizes, int n_in,
                              void* d_out, int out_size, void* d_ws, size_t ws_size,
                              hipStream_t stream) {
    const float* z_pres = (const float*)d_in[0];      // setup_inputs order
    const float* z_prob = (const float*)d_in[1];
    float* out = (float*)d_out;
    const int nbatch = in_sizes[0] / HW;              // 1024
    spair_count_kl<<<dim3(nbatch), dim3(64), 0, stream>>>(z_pres, z_prob, out);
}